// Round 3
// baseline (4008.082 us; speedup 1.0000x reference)
//
#include <hip/hip_runtime.h>
#include <math.h>

#define ISQ2 0.70710678118654752440f

static __device__ __constant__ float H0c[13] = {
    -0.0017578f, 0.0f, 0.0222656f, -0.046875f, -0.0482422f, 0.296875f,
    0.5554688f, 0.296875f, -0.0482422f, -0.046875f, 0.0222656f, 0.0f, -0.0017578f};
static __device__ __constant__ float H1c[19] = {
    -7.06e-05f, 0.0f, 0.0013419f, -0.0018834f, -0.0071568f, 0.023856f,
    0.0556431f, -0.0516881f, -0.2997576f, 0.5594308f, -0.2997576f, -0.0516881f,
    0.0556431f, 0.023856f, -0.0071568f, -0.0018834f, 0.0013419f, 0.0f, -7.06e-05f};

__device__ __forceinline__ int refl32(int i) {
    if (i < 0) i = -1 - i;
    if (i > 31) i = 63 - i;
    return i;
}

__device__ __forceinline__ float gelu_exact(float x) {
    return 0.5f * x * (1.0f + erff(x * ISQ2));
}

__device__ __forceinline__ float bf2f(unsigned short u) {
    union { unsigned int i; float f; } v;
    v.i = ((unsigned int)u) << 16;
    return v.f;
}

__device__ __forceinline__ unsigned int packbf2(float a, float b) {
    // round-to-nearest-even bf16 pack
    union { float f; unsigned int i; } ua, ub;
    ua.f = a; ub.f = b;
    unsigned int ra = ua.i + 0x7FFF + ((ua.i >> 16) & 1);
    unsigned int rb = ub.i + 0x7FFF + ((ub.i >> 16) & 1);
    return (ra >> 16) | (rb & 0xFFFF0000u);
}

// ---------------- K1: LN1 + transpose (B,N,C)->(B,C,32,32) ----------------
__global__ __launch_bounds__(256) void k_ln1_t(const float* __restrict__ x,
                                               const float* __restrict__ g,
                                               const float* __restrict__ be,
                                               float* __restrict__ A) {
    __shared__ float sx[64][65];
    __shared__ float rs[64][4], rq[64][4];
    __shared__ float sm[64], sv[64];
    int b = blockIdx.x >> 4;
    int n0 = (blockIdx.x & 15) << 6;
    int tid = threadIdx.x;
    const float* xp = x + ((size_t)b * 1024 + n0) * 64;
#pragma unroll
    for (int rep = 0; rep < 16; ++rep) {
        int idx = rep * 256 + tid;
        sx[idx >> 6][idx & 63] = xp[idx];
    }
    __syncthreads();
    {
        int i = tid >> 2, q = tid & 3;
        float s = 0.f, ss = 0.f;
#pragma unroll
        for (int d = 0; d < 16; ++d) {
            float v = sx[i][q * 16 + d];
            s += v; ss += v * v;
        }
        rs[i][q] = s; rq[i][q] = ss;
    }
    __syncthreads();
    if (tid < 64) {
        float s = rs[tid][0] + rs[tid][1] + rs[tid][2] + rs[tid][3];
        float ss = rq[tid][0] + rq[tid][1] + rq[tid][2] + rq[tid][3];
        float m = s * (1.f / 64.f);
        float v = ss * (1.f / 64.f) - m * m;
        sm[tid] = m;
        sv[tid] = rsqrtf(v + 1e-5f);
    }
    __syncthreads();
#pragma unroll
    for (int rep = 0; rep < 16; ++rep) {
        int idx = rep * 256 + tid;
        int c = idx >> 6, i = idx & 63;
        float val = (sx[i][c] - sm[i]) * sv[i] * g[c] + be[c];
        A[((size_t)(b * 64 + c)) * 1024 + n0 + i] = val;
    }
}

// ---------------- K2: forward DTCWT per (b,c) image ----------------
__device__ __forceinline__ float col19(const float (*arr)[33], int h, int w) {
    float s = 0.f;
#pragma unroll
    for (int k = 0; k < 19; ++k) s += H1c[k] * arr[refl32(h + k - 9)][w];
    return s;
}
__device__ __forceinline__ float col13(const float (*arr)[33], int h, int w) {
    float s = 0.f;
#pragma unroll
    for (int k = 0; k < 13; ++k) s += H0c[k] * arr[refl32(h + k - 6)][w];
    return s;
}

__global__ __launch_bounds__(256) void k_fwd(const float* __restrict__ A,
                                             const float* __restrict__ wll,
                                             float* __restrict__ LL,
                                             float* __restrict__ HSr,
                                             float* __restrict__ HSi) {
    __shared__ float sx[32][33], slo[32][33], shi[32][33];
    int bc = blockIdx.x;
    int c = bc & 63;
    int tid = threadIdx.x;
    const float* ap = A + (size_t)bc * 1024;
#pragma unroll
    for (int r = 0; r < 4; ++r) {
        int p = r * 256 + tid;
        sx[p >> 5][p & 31] = ap[p];
    }
    __syncthreads();
#pragma unroll
    for (int r = 0; r < 4; ++r) {
        int p = r * 256 + tid;
        int h = p >> 5, w = p & 31;
        float lo = 0.f, hi = 0.f;
#pragma unroll
        for (int k = 0; k < 13; ++k) lo += H0c[k] * sx[h][refl32(w + k - 6)];
#pragma unroll
        for (int k = 0; k < 19; ++k) hi += H1c[k] * sx[h][refl32(w + k - 9)];
        slo[h][w] = lo;
        shi[h][w] = hi;
    }
    __syncthreads();
#pragma unroll
    for (int r = 0; r < 4; ++r) {
        int p = r * 256 + tid;
        int h = p >> 5, w = p & 31;
        float acc = 0.f;
#pragma unroll
        for (int k = 0; k < 13; ++k) acc += H0c[k] * slo[refl32(h + k - 6)][w];
        LL[(size_t)bc * 1024 + p] = acc * wll[c * 1024 + p];
    }
    {
        int p = tid;
        int i = p >> 4, j = p & 15;
        int h0 = 2 * i, w0 = 2 * j;
        size_t base = (size_t)bc * 1536 + p;
        float a, bb, cc, dd;
        a = col19(slo, h0, w0); bb = col19(slo, h0, w0 + 1);
        cc = col19(slo, h0 + 1, w0); dd = col19(slo, h0 + 1, w0 + 1);
        HSr[base + 0 * 256] = (a - dd) * ISQ2; HSi[base + 0 * 256] = (bb + cc) * ISQ2;
        HSr[base + 5 * 256] = (a + dd) * ISQ2; HSi[base + 5 * 256] = (bb - cc) * ISQ2;
        a = col19(shi, h0, w0); bb = col19(shi, h0, w0 + 1);
        cc = col19(shi, h0 + 1, w0); dd = col19(shi, h0 + 1, w0 + 1);
        HSr[base + 1 * 256] = (a - dd) * ISQ2; HSi[base + 1 * 256] = (bb + cc) * ISQ2;
        HSr[base + 4 * 256] = (a + dd) * ISQ2; HSi[base + 4 * 256] = (bb - cc) * ISQ2;
        a = col13(shi, h0, w0); bb = col13(shi, h0, w0 + 1);
        cc = col13(shi, h0 + 1, w0); dd = col13(shi, h0 + 1, w0 + 1);
        HSr[base + 2 * 256] = (a - dd) * ISQ2; HSi[base + 2 * 256] = (bb + cc) * ISQ2;
        HSr[base + 3 * 256] = (a + dd) * ISQ2; HSi[base + 3 * 256] = (bb - cc) * ISQ2;
    }
}

// ---------------- K3: complex block-diagonal MLP (in-place on HS) ----------------
__global__ __launch_bounds__(256) void k_mlp(float* __restrict__ HSr,
                                             float* __restrict__ HSi,
                                             const float* __restrict__ w1,
                                             const float* __restrict__ w2,
                                             const float* __restrict__ b1,
                                             const float* __restrict__ b2) {
    __shared__ float sr[64][65], si[64][65];
    __shared__ float w1s[2048], w2s[2048], b1s[128], b2s[128];
    int blk = blockIdx.x;
    int b = blk / 24;
    int rem = blk % 24;
    int o = rem >> 2;
    int ij0 = (rem & 3) << 6;
    int tid = threadIdx.x;
    for (int idx = tid; idx < 2048; idx += 256) {
        w1s[idx] = w1[idx];
        w2s[idx] = w2[idx];
    }
    if (tid < 128) { b1s[tid] = b1[tid]; b2s[tid] = b2[tid]; }
#pragma unroll
    for (int rep = 0; rep < 16; ++rep) {
        int idx = rep * 256 + tid;
        int c = idx >> 6, j = idx & 63;
        size_t gi = ((size_t)(b * 64 + c) * 6 + o) * 256 + ij0 + j;
        sr[c][j] = HSr[gi];
        si[c][j] = HSi[gi];
    }
    __syncthreads();
    {
        int j = tid & 63, q = tid >> 6;
        float xr[16], xi[16];
#pragma unroll
        for (int d = 0; d < 16; ++d) {
            xr[d] = sr[q * 16 + d][j];
            xi[d] = si[q * 16 + d][j];
        }
        float r1[16], i1[16];
#pragma unroll
        for (int k = 0; k < 16; ++k) {
            float ar = b1s[q * 16 + k];
            float ai = b1s[64 + q * 16 + k];
#pragma unroll
            for (int d = 0; d < 16; ++d) {
                float wr = w1s[q * 256 + d * 16 + k];
                float wi = w1s[1024 + q * 256 + d * 16 + k];
                ar += xr[d] * wr - xi[d] * wi;
                ai += xr[d] * wi + xi[d] * wr;
            }
            r1[k] = fmaxf(ar, 0.f);
            i1[k] = fmaxf(ai, 0.f);
        }
#pragma unroll
        for (int k = 0; k < 16; ++k) {
            float ar = b2s[q * 16 + k];
            float ai = b2s[64 + q * 16 + k];
#pragma unroll
            for (int d = 0; d < 16; ++d) {
                float wr = w2s[q * 256 + d * 16 + k];
                float wi = w2s[1024 + q * 256 + d * 16 + k];
                ar += r1[d] * wr - i1[d] * wi;
                ai += r1[d] * wi + i1[d] * wr;
            }
            sr[q * 16 + k][j] = ar;
            si[q * 16 + k][j] = ai;
        }
    }
    __syncthreads();
#pragma unroll
    for (int rep = 0; rep < 16; ++rep) {
        int idx = rep * 256 + tid;
        int c = idx >> 6, j = idx & 63;
        size_t gi = ((size_t)(b * 64 + c) * 6 + o) * 256 + ij0 + j;
        HSr[gi] = sr[c][j];
        HSi[gi] = si[c][j];
    }
}

// ---------------- K4: inverse DTCWT per (b,c) -> Y (B,C,N) ----------------
__global__ __launch_bounds__(256) void k_inv(const float* __restrict__ LL,
                                             const float* __restrict__ HSr,
                                             const float* __restrict__ HSi,
                                             float* __restrict__ Y) {
    __shared__ float sll[32][33], slh[32][33], shl[32][33], shh[32][33];
    __shared__ float slo[32][33], shi[32][33];
    int bc = blockIdx.x;
    int tid = threadIdx.x;
    const float* lp = LL + (size_t)bc * 1024;
#pragma unroll
    for (int r = 0; r < 4; ++r) {
        int p = r * 256 + tid;
        sll[p >> 5][p & 31] = lp[p];
    }
    {
        int p = tid;
        int i = p >> 4, j = p & 15;
        int h0 = 2 * i, w0 = 2 * j;
        size_t base = (size_t)bc * 1536 + p;
        float o0r = HSr[base + 0 * 256], o0i = HSi[base + 0 * 256];
        float o1r = HSr[base + 1 * 256], o1i = HSi[base + 1 * 256];
        float o2r = HSr[base + 2 * 256], o2i = HSi[base + 2 * 256];
        float o3r = HSr[base + 3 * 256], o3i = HSi[base + 3 * 256];
        float o4r = HSr[base + 4 * 256], o4i = HSi[base + 4 * 256];
        float o5r = HSr[base + 5 * 256], o5i = HSi[base + 5 * 256];
        slh[h0][w0] = (o0r + o5r) * ISQ2;
        slh[h0][w0 + 1] = (o0i + o5i) * ISQ2;
        slh[h0 + 1][w0] = (o0i - o5i) * ISQ2;
        slh[h0 + 1][w0 + 1] = (o5r - o0r) * ISQ2;
        shl[h0][w0] = (o2r + o3r) * ISQ2;
        shl[h0][w0 + 1] = (o2i + o3i) * ISQ2;
        shl[h0 + 1][w0] = (o2i - o3i) * ISQ2;
        shl[h0 + 1][w0 + 1] = (o3r - o2r) * ISQ2;
        shh[h0][w0] = (o1r + o4r) * ISQ2;
        shh[h0][w0 + 1] = (o1i + o4i) * ISQ2;
        shh[h0 + 1][w0] = (o1i - o4i) * ISQ2;
        shh[h0 + 1][w0 + 1] = (o4r - o1r) * ISQ2;
    }
    __syncthreads();
#pragma unroll
    for (int r = 0; r < 4; ++r) {
        int p = r * 256 + tid;
        int h = p >> 5, w = p & 31;
        float lo = 0.f, hi = 0.f;
#pragma unroll
        for (int k = 0; k < 19; ++k) {
            float g0 = (k & 1) ? H1c[k] : -H1c[k];
            int hh2 = refl32(h + k - 9);
            lo += g0 * sll[hh2][w];
            hi += g0 * shl[hh2][w];
        }
#pragma unroll
        for (int k = 0; k < 13; ++k) {
            float g1 = (k & 1) ? H0c[k] : -H0c[k];
            int hh2 = refl32(h + k - 6);
            lo += g1 * slh[hh2][w];
            hi += g1 * shh[hh2][w];
        }
        slo[h][w] = lo;
        shi[h][w] = hi;
    }
    __syncthreads();
#pragma unroll
    for (int r = 0; r < 4; ++r) {
        int p = r * 256 + tid;
        int h = p >> 5, w = p & 31;
        float y = 0.f;
#pragma unroll
        for (int k = 0; k < 19; ++k) {
            float g0 = (k & 1) ? H1c[k] : -H1c[k];
            y += g0 * slo[h][refl32(w + k - 9)];
        }
#pragma unroll
        for (int k = 0; k < 13; ++k) {
            float g1 = (k & 1) ? H0c[k] : -H0c[k];
            y += g1 * shi[h][refl32(w + k - 6)];
        }
        Y[(size_t)bc * 1024 + p] = y;
    }
}

// ---------------- K4b: X1 = x + Y^T -> d_out (B,N,C) ----------------
__global__ __launch_bounds__(256) void k_addt(const float* __restrict__ Y,
                                              const float* __restrict__ x,
                                              float* __restrict__ out) {
    __shared__ float sy[64][65];
    int b = blockIdx.x >> 4;
    int n0 = (blockIdx.x & 15) << 6;
    int tid = threadIdx.x;
#pragma unroll
    for (int rep = 0; rep < 16; ++rep) {
        int idx = rep * 256 + tid;
        int c = idx >> 6, i = idx & 63;
        sy[c][i] = Y[((size_t)(b * 64 + c)) * 1024 + n0 + i];
    }
    __syncthreads();
#pragma unroll
    for (int rep = 0; rep < 16; ++rep) {
        int idx = rep * 256 + tid;
        int i = idx >> 6, c = idx & 63;
        size_t gi = ((size_t)b * 1024 + n0 + i) * 64 + c;
        out[gi] = x[gi] + sy[c][i];
    }
}

// ---------------- K5: LN2 + lin1 + GELU -> H1 bf16 (B,N,256) ----------------
// token-per-lane, LN + activations fully in registers, wave-uniform weights.
__global__ __launch_bounds__(256) void k_leff1(const float* __restrict__ X1,
                                               const float* __restrict__ g2,
                                               const float* __restrict__ be2,
                                               const float* __restrict__ W1,
                                               const float* __restrict__ B1,
                                               unsigned short* __restrict__ H1b) {
    int tid = threadIdx.x;
    size_t tok = (size_t)blockIdx.x * 256 + tid;
    const float4* xp4 = (const float4*)(X1 + tok * 64);
    float4 xv[16];
    float s = 0.f, ss = 0.f;
#pragma unroll
    for (int i = 0; i < 16; ++i) {
        float4 v = xp4[i];
        s += v.x + v.y + v.z + v.w;
        ss += v.x * v.x + v.y * v.y + v.z * v.z + v.w * v.w;
        xv[i] = v;
    }
    float m = s * (1.f / 64.f);
    float var = ss * (1.f / 64.f) - m * m;
    float rstd = rsqrtf(var + 1e-5f);
    float xn[64];
#pragma unroll
    for (int i = 0; i < 16; ++i) {
        xn[4 * i + 0] = (xv[i].x - m) * rstd * g2[4 * i + 0] + be2[4 * i + 0];
        xn[4 * i + 1] = (xv[i].y - m) * rstd * g2[4 * i + 1] + be2[4 * i + 1];
        xn[4 * i + 2] = (xv[i].z - m) * rstd * g2[4 * i + 2] + be2[4 * i + 2];
        xn[4 * i + 3] = (xv[i].w - m) * rstd * g2[4 * i + 3] + be2[4 * i + 3];
    }
    const float4* W1v = (const float4*)W1;  // row d: 64 float4
    const float4* B1v = (const float4*)B1;
#pragma unroll 1
    for (int cp = 0; cp < 8; ++cp) {
        float4 acc[8];
#pragma unroll
        for (int j = 0; j < 8; ++j) acc[j] = B1v[cp * 8 + j];
#pragma unroll
        for (int d = 0; d < 64; ++d) {
            float xd = xn[d];
#pragma unroll
            for (int j = 0; j < 8; ++j) {
                float4 w = W1v[d * 64 + cp * 8 + j];
                acc[j].x += xd * w.x;
                acc[j].y += xd * w.y;
                acc[j].z += xd * w.z;
                acc[j].w += xd * w.w;
            }
        }
        unsigned int us[16];
#pragma unroll
        for (int j = 0; j < 8; ++j) {
            float4 a = acc[j];
            a.x = gelu_exact(a.x);
            a.y = gelu_exact(a.y);
            a.z = gelu_exact(a.z);
            a.w = gelu_exact(a.w);
            us[2 * j] = packbf2(a.x, a.y);
            us[2 * j + 1] = packbf2(a.z, a.w);
        }
        uint4* hp = (uint4*)(H1b + tok * 256 + cp * 32);
        hp[0] = make_uint4(us[0], us[1], us[2], us[3]);
        hp[1] = make_uint4(us[4], us[5], us[6], us[7]);
        hp[2] = make_uint4(us[8], us[9], us[10], us[11]);
        hp[3] = make_uint4(us[12], us[13], us[14], us[15]);
    }
}

// ---------------- K6: dwconv3x3 + GELU + lin2 + bias + residual -> out ----------
// 2048 blocks = (b, 4-row strip); 2 lanes/token; 8 chunks of 32 hid;
// LDS tile 32x205 f32 (odd stride => conflict-free); scalar weights.
__global__ __launch_bounds__(256) void k_leff2(const unsigned short* __restrict__ H1b,
                                               const float* __restrict__ DW,
                                               const float* __restrict__ DB,
                                               const float* __restrict__ W2,
                                               const float* __restrict__ B2,
                                               float* __restrict__ out) {
    __shared__ float tile[32 * 205];
    int tid = threadIdx.x;
    int b = blockIdx.x >> 3;
    int strip = blockIdx.x & 7;
    int p = tid & 1;
    int tok = tid >> 1;            // 0..127
    int r = tok >> 5, w = tok & 31;
    int h_img = strip * 4 + r;

    float4 acc[8];
#pragma unroll
    for (int j = 0; j < 8; ++j) acc[j] = make_float4(0.f, 0.f, 0.f, 0.f);

    const float4* W2v = (const float4*)W2;  // row hid: 16 float4
#pragma unroll 1
    for (int cc = 0; cc < 8; ++cc) {
        __syncthreads();
        for (int idx = tid; idx < 6528; idx += 256) {
            int hid_l = idx & 31;
            int rest = idx >> 5;       // 0..203
            int tr = rest / 34;
            int wt = rest - tr * 34;
            int hr = strip * 4 - 1 + tr;
            int wi = wt - 1;
            float v = 0.f;
            if (hr >= 0 && hr < 32 && wi >= 0 && wi < 32)
                v = bf2f(H1b[((size_t)b * 1024 + hr * 32 + wi) * 256 + cc * 32 + hid_l]);
            tile[hid_l * 205 + rest] = v;
        }
        __syncthreads();
#pragma unroll 2
        for (int hl = 0; hl < 32; ++hl) {
            int hid = cc * 32 + hl;
            const float* tp = &tile[hl * 205 + r * 34 + w];
            float g = 0.f;
#pragma unroll
            for (int dr = 0; dr < 3; ++dr) {
#pragma unroll
                for (int dwx = 0; dwx < 3; ++dwx) {
                    g += tp[dr * 34 + dwx] * DW[hid * 9 + dr * 3 + dwx];
                }
            }
            g = gelu_exact(g + DB[hid]);
#pragma unroll
            for (int j = 0; j < 8; ++j) {
                float4 w4 = W2v[hid * 16 + p * 8 + j];
                acc[j].x += g * w4.x;
                acc[j].y += g * w4.y;
                acc[j].z += g * w4.z;
                acc[j].w += g * w4.w;
            }
        }
    }
    size_t tokg = (size_t)b * 1024 + h_img * 32 + w;
    const float4* B2v = (const float4*)B2;
    float4* outv = (float4*)(out + tokg * 64 + p * 32);
#pragma unroll
    for (int j = 0; j < 8; ++j) {
        float4 o = outv[j];
        float4 b4 = B2v[p * 8 + j];
        o.x += acc[j].x + b4.x;
        o.y += acc[j].y + b4.y;
        o.z += acc[j].z + b4.z;
        o.w += acc[j].w + b4.w;
        outv[j] = o;
    }
}

extern "C" void kernel_launch(void* const* d_in, const int* in_sizes, int n_in,
                              void* d_out, int out_size, void* d_ws, size_t ws_size,
                              hipStream_t stream) {
    const float* x = (const float*)d_in[0];
    const float* ln1_g = (const float*)d_in[1];
    const float* ln1_b = (const float*)d_in[2];
    const float* w_ll = (const float*)d_in[3];
    const float* w1 = (const float*)d_in[4];
    const float* w2 = (const float*)d_in[5];
    const float* b1 = (const float*)d_in[6];
    const float* b2 = (const float*)d_in[7];
    const float* ln2_g = (const float*)d_in[8];
    const float* ln2_b = (const float*)d_in[9];
    const float* lin1_w = (const float*)d_in[10];
    const float* lin1_b = (const float*)d_in[11];
    const float* dw_w = (const float*)d_in[12];
    const float* dw_b = (const float*)d_in[13];
    const float* lin2_w = (const float*)d_in[14];
    const float* lin2_b = (const float*)d_in[15];
    float* out = (float*)d_out;
    char* ws = (char*)d_ws;

    float* A = (float*)ws;
    float* HSr = (float*)(ws + 67108864);
    float* HSi = (float*)(ws + 167772160);
    float* LL = out;
    float* Y = A;
    unsigned short* H1b = (unsigned short*)ws;  // 134 MB, A/Y dead by then

    k_ln1_t<<<dim3(4096), dim3(256), 0, stream>>>(x, ln1_g, ln1_b, A);
    k_fwd<<<dim3(16384), dim3(256), 0, stream>>>(A, w_ll, LL, HSr, HSi);
    k_mlp<<<dim3(6144), dim3(256), 0, stream>>>(HSr, HSi, w1, w2, b1, b2);
    k_inv<<<dim3(16384), dim3(256), 0, stream>>>(LL, HSr, HSi, Y);
    k_addt<<<dim3(4096), dim3(256), 0, stream>>>(Y, x, out);
    k_leff1<<<dim3(1024), dim3(256), 0, stream>>>(out, ln2_g, ln2_b, lin1_w, lin1_b, H1b);
    k_leff2<<<dim3(2048), dim3(256), 0, stream>>>(H1b, dw_w, dw_b, lin2_w, lin2_b, out);
}

// Round 4
// 1388.895 us; speedup vs baseline: 2.8858x; 2.8858x over previous
//
#include <hip/hip_runtime.h>
#include <math.h>

#define ISQ2 0.70710678118654752440f

static __device__ __constant__ float H0c[13] = {
    -0.0017578f, 0.0f, 0.0222656f, -0.046875f, -0.0482422f, 0.296875f,
    0.5554688f, 0.296875f, -0.0482422f, -0.046875f, 0.0222656f, 0.0f, -0.0017578f};
static __device__ __constant__ float H1c[19] = {
    -7.06e-05f, 0.0f, 0.0013419f, -0.0018834f, -0.0071568f, 0.023856f,
    0.0556431f, -0.0516881f, -0.2997576f, 0.5594308f, -0.2997576f, -0.0516881f,
    0.0556431f, 0.023856f, -0.0071568f, -0.0018834f, 0.0013419f, 0.0f, -7.06e-05f};

__device__ __forceinline__ int refl32(int i) {
    if (i < 0) i = -1 - i;
    if (i > 31) i = 63 - i;
    return i;
}

__device__ __forceinline__ float gelu_exact(float x) {
    return 0.5f * x * (1.0f + erff(x * ISQ2));
}

__device__ __forceinline__ float bf2f(unsigned short u) {
    union { unsigned int i; float f; } v;
    v.i = ((unsigned int)u) << 16;
    return v.f;
}

__device__ __forceinline__ unsigned short f2bf(float a) {
    union { float f; unsigned int i; } ua;
    ua.f = a;
    unsigned int r = ua.i + 0x7FFF + ((ua.i >> 16) & 1);
    return (unsigned short)(r >> 16);
}

// ---------------- K1: LN1 + transpose (B,N,C)->(B,C,32,32) ----------------
__global__ __launch_bounds__(256) void k_ln1_t(const float* __restrict__ x,
                                               const float* __restrict__ g,
                                               const float* __restrict__ be,
                                               float* __restrict__ A) {
    __shared__ float sx[64][65];
    __shared__ float rs[64][4], rq[64][4];
    __shared__ float sm[64], sv[64];
    int b = blockIdx.x >> 4;
    int n0 = (blockIdx.x & 15) << 6;
    int tid = threadIdx.x;
    const float* xp = x + ((size_t)b * 1024 + n0) * 64;
#pragma unroll
    for (int rep = 0; rep < 16; ++rep) {
        int idx = rep * 256 + tid;
        sx[idx >> 6][idx & 63] = xp[idx];
    }
    __syncthreads();
    {
        int i = tid >> 2, q = tid & 3;
        float s = 0.f, ss = 0.f;
#pragma unroll
        for (int d = 0; d < 16; ++d) {
            float v = sx[i][q * 16 + d];
            s += v; ss += v * v;
        }
        rs[i][q] = s; rq[i][q] = ss;
    }
    __syncthreads();
    if (tid < 64) {
        float s = rs[tid][0] + rs[tid][1] + rs[tid][2] + rs[tid][3];
        float ss = rq[tid][0] + rq[tid][1] + rq[tid][2] + rq[tid][3];
        float m = s * (1.f / 64.f);
        float v = ss * (1.f / 64.f) - m * m;
        sm[tid] = m;
        sv[tid] = rsqrtf(v + 1e-5f);
    }
    __syncthreads();
#pragma unroll
    for (int rep = 0; rep < 16; ++rep) {
        int idx = rep * 256 + tid;
        int c = idx >> 6, i = idx & 63;
        float val = (sx[i][c] - sm[i]) * sv[i] * g[c] + be[c];
        A[((size_t)(b * 64 + c)) * 1024 + n0 + i] = val;
    }
}

// ---------------- K2: forward DTCWT per (b,c) image ----------------
__device__ __forceinline__ float col19(const float (*arr)[33], int h, int w) {
    float s = 0.f;
#pragma unroll
    for (int k = 0; k < 19; ++k) s += H1c[k] * arr[refl32(h + k - 9)][w];
    return s;
}
__device__ __forceinline__ float col13(const float (*arr)[33], int h, int w) {
    float s = 0.f;
#pragma unroll
    for (int k = 0; k < 13; ++k) s += H0c[k] * arr[refl32(h + k - 6)][w];
    return s;
}

__global__ __launch_bounds__(256) void k_fwd(const float* __restrict__ A,
                                             const float* __restrict__ wll,
                                             float* __restrict__ LL,
                                             float* __restrict__ HSr,
                                             float* __restrict__ HSi) {
    __shared__ float sx[32][33], slo[32][33], shi[32][33];
    int bc = blockIdx.x;
    int c = bc & 63;
    int tid = threadIdx.x;
    const float* ap = A + (size_t)bc * 1024;
#pragma unroll
    for (int r = 0; r < 4; ++r) {
        int p = r * 256 + tid;
        sx[p >> 5][p & 31] = ap[p];
    }
    __syncthreads();
#pragma unroll
    for (int r = 0; r < 4; ++r) {
        int p = r * 256 + tid;
        int h = p >> 5, w = p & 31;
        float lo = 0.f, hi = 0.f;
#pragma unroll
        for (int k = 0; k < 13; ++k) lo += H0c[k] * sx[h][refl32(w + k - 6)];
#pragma unroll
        for (int k = 0; k < 19; ++k) hi += H1c[k] * sx[h][refl32(w + k - 9)];
        slo[h][w] = lo;
        shi[h][w] = hi;
    }
    __syncthreads();
#pragma unroll
    for (int r = 0; r < 4; ++r) {
        int p = r * 256 + tid;
        int h = p >> 5, w = p & 31;
        float acc = 0.f;
#pragma unroll
        for (int k = 0; k < 13; ++k) acc += H0c[k] * slo[refl32(h + k - 6)][w];
        LL[(size_t)bc * 1024 + p] = acc * wll[c * 1024 + p];
    }
    {
        int p = tid;
        int i = p >> 4, j = p & 15;
        int h0 = 2 * i, w0 = 2 * j;
        size_t base = (size_t)bc * 1536 + p;
        float a, bb, cc, dd;
        a = col19(slo, h0, w0); bb = col19(slo, h0, w0 + 1);
        cc = col19(slo, h0 + 1, w0); dd = col19(slo, h0 + 1, w0 + 1);
        HSr[base + 0 * 256] = (a - dd) * ISQ2; HSi[base + 0 * 256] = (bb + cc) * ISQ2;
        HSr[base + 5 * 256] = (a + dd) * ISQ2; HSi[base + 5 * 256] = (bb - cc) * ISQ2;
        a = col19(shi, h0, w0); bb = col19(shi, h0, w0 + 1);
        cc = col19(shi, h0 + 1, w0); dd = col19(shi, h0 + 1, w0 + 1);
        HSr[base + 1 * 256] = (a - dd) * ISQ2; HSi[base + 1 * 256] = (bb + cc) * ISQ2;
        HSr[base + 4 * 256] = (a + dd) * ISQ2; HSi[base + 4 * 256] = (bb - cc) * ISQ2;
        a = col13(shi, h0, w0); bb = col13(shi, h0, w0 + 1);
        cc = col13(shi, h0 + 1, w0); dd = col13(shi, h0 + 1, w0 + 1);
        HSr[base + 2 * 256] = (a - dd) * ISQ2; HSi[base + 2 * 256] = (bb + cc) * ISQ2;
        HSr[base + 3 * 256] = (a + dd) * ISQ2; HSi[base + 3 * 256] = (bb - cc) * ISQ2;
    }
}

// ---------------- K3: complex block-diagonal MLP (in-place on HS) ----------------
__global__ __launch_bounds__(256) void k_mlp(float* __restrict__ HSr,
                                             float* __restrict__ HSi,
                                             const float* __restrict__ w1,
                                             const float* __restrict__ w2,
                                             const float* __restrict__ b1,
                                             const float* __restrict__ b2) {
    __shared__ float sr[64][65], si[64][65];
    __shared__ float w1s[2048], w2s[2048], b1s[128], b2s[128];
    int blk = blockIdx.x;
    int b = blk / 24;
    int rem = blk % 24;
    int o = rem >> 2;
    int ij0 = (rem & 3) << 6;
    int tid = threadIdx.x;
    for (int idx = tid; idx < 2048; idx += 256) {
        w1s[idx] = w1[idx];
        w2s[idx] = w2[idx];
    }
    if (tid < 128) { b1s[tid] = b1[tid]; b2s[tid] = b2[tid]; }
#pragma unroll
    for (int rep = 0; rep < 16; ++rep) {
        int idx = rep * 256 + tid;
        int c = idx >> 6, j = idx & 63;
        size_t gi = ((size_t)(b * 64 + c) * 6 + o) * 256 + ij0 + j;
        sr[c][j] = HSr[gi];
        si[c][j] = HSi[gi];
    }
    __syncthreads();
    {
        int j = tid & 63, q = tid >> 6;
        float xr[16], xi[16];
#pragma unroll
        for (int d = 0; d < 16; ++d) {
            xr[d] = sr[q * 16 + d][j];
            xi[d] = si[q * 16 + d][j];
        }
        float r1[16], i1[16];
#pragma unroll
        for (int k = 0; k < 16; ++k) {
            float ar = b1s[q * 16 + k];
            float ai = b1s[64 + q * 16 + k];
#pragma unroll
            for (int d = 0; d < 16; ++d) {
                float wr = w1s[q * 256 + d * 16 + k];
                float wi = w1s[1024 + q * 256 + d * 16 + k];
                ar += xr[d] * wr - xi[d] * wi;
                ai += xr[d] * wi + xi[d] * wr;
            }
            r1[k] = fmaxf(ar, 0.f);
            i1[k] = fmaxf(ai, 0.f);
        }
#pragma unroll
        for (int k = 0; k < 16; ++k) {
            float ar = b2s[q * 16 + k];
            float ai = b2s[64 + q * 16 + k];
#pragma unroll
            for (int d = 0; d < 16; ++d) {
                float wr = w2s[q * 256 + d * 16 + k];
                float wi = w2s[1024 + q * 256 + d * 16 + k];
                ar += r1[d] * wr - i1[d] * wi;
                ai += r1[d] * wi + i1[d] * wr;
            }
            sr[q * 16 + k][j] = ar;
            si[q * 16 + k][j] = ai;
        }
    }
    __syncthreads();
#pragma unroll
    for (int rep = 0; rep < 16; ++rep) {
        int idx = rep * 256 + tid;
        int c = idx >> 6, j = idx & 63;
        size_t gi = ((size_t)(b * 64 + c) * 6 + o) * 256 + ij0 + j;
        HSr[gi] = sr[c][j];
        HSi[gi] = si[c][j];
    }
}

// ---------------- K4: inverse DTCWT per (b,c) -> Y (B,C,N) ----------------
__global__ __launch_bounds__(256) void k_inv(const float* __restrict__ LL,
                                             const float* __restrict__ HSr,
                                             const float* __restrict__ HSi,
                                             float* __restrict__ Y) {
    __shared__ float sll[32][33], slh[32][33], shl[32][33], shh[32][33];
    __shared__ float slo[32][33], shi[32][33];
    int bc = blockIdx.x;
    int tid = threadIdx.x;
    const float* lp = LL + (size_t)bc * 1024;
#pragma unroll
    for (int r = 0; r < 4; ++r) {
        int p = r * 256 + tid;
        sll[p >> 5][p & 31] = lp[p];
    }
    {
        int p = tid;
        int i = p >> 4, j = p & 15;
        int h0 = 2 * i, w0 = 2 * j;
        size_t base = (size_t)bc * 1536 + p;
        float o0r = HSr[base + 0 * 256], o0i = HSi[base + 0 * 256];
        float o1r = HSr[base + 1 * 256], o1i = HSi[base + 1 * 256];
        float o2r = HSr[base + 2 * 256], o2i = HSi[base + 2 * 256];
        float o3r = HSr[base + 3 * 256], o3i = HSi[base + 3 * 256];
        float o4r = HSr[base + 4 * 256], o4i = HSi[base + 4 * 256];
        float o5r = HSr[base + 5 * 256], o5i = HSi[base + 5 * 256];
        slh[h0][w0] = (o0r + o5r) * ISQ2;
        slh[h0][w0 + 1] = (o0i + o5i) * ISQ2;
        slh[h0 + 1][w0] = (o0i - o5i) * ISQ2;
        slh[h0 + 1][w0 + 1] = (o5r - o0r) * ISQ2;
        shl[h0][w0] = (o2r + o3r) * ISQ2;
        shl[h0][w0 + 1] = (o2i + o3i) * ISQ2;
        shl[h0 + 1][w0] = (o2i - o3i) * ISQ2;
        shl[h0 + 1][w0 + 1] = (o3r - o2r) * ISQ2;
        shh[h0][w0] = (o1r + o4r) * ISQ2;
        shh[h0][w0 + 1] = (o1i + o4i) * ISQ2;
        shh[h0 + 1][w0] = (o1i - o4i) * ISQ2;
        shh[h0 + 1][w0 + 1] = (o4r - o1r) * ISQ2;
    }
    __syncthreads();
#pragma unroll
    for (int r = 0; r < 4; ++r) {
        int p = r * 256 + tid;
        int h = p >> 5, w = p & 31;
        float lo = 0.f, hi = 0.f;
#pragma unroll
        for (int k = 0; k < 19; ++k) {
            float g0 = (k & 1) ? H1c[k] : -H1c[k];
            int hh2 = refl32(h + k - 9);
            lo += g0 * sll[hh2][w];
            hi += g0 * shl[hh2][w];
        }
#pragma unroll
        for (int k = 0; k < 13; ++k) {
            float g1 = (k & 1) ? H0c[k] : -H0c[k];
            int hh2 = refl32(h + k - 6);
            lo += g1 * slh[hh2][w];
            hi += g1 * shh[hh2][w];
        }
        slo[h][w] = lo;
        shi[h][w] = hi;
    }
    __syncthreads();
#pragma unroll
    for (int r = 0; r < 4; ++r) {
        int p = r * 256 + tid;
        int h = p >> 5, w = p & 31;
        float y = 0.f;
#pragma unroll
        for (int k = 0; k < 19; ++k) {
            float g0 = (k & 1) ? H1c[k] : -H1c[k];
            y += g0 * slo[h][refl32(w + k - 9)];
        }
#pragma unroll
        for (int k = 0; k < 13; ++k) {
            float g1 = (k & 1) ? H0c[k] : -H0c[k];
            y += g1 * shi[h][refl32(w + k - 6)];
        }
        Y[(size_t)bc * 1024 + p] = y;
    }
}

// ---------------- K4b: X1 = x + Y^T -> d_out (B,N,C) ----------------
__global__ __launch_bounds__(256) void k_addt(const float* __restrict__ Y,
                                              const float* __restrict__ x,
                                              float* __restrict__ out) {
    __shared__ float sy[64][65];
    int b = blockIdx.x >> 4;
    int n0 = (blockIdx.x & 15) << 6;
    int tid = threadIdx.x;
#pragma unroll
    for (int rep = 0; rep < 16; ++rep) {
        int idx = rep * 256 + tid;
        int c = idx >> 6, i = idx & 63;
        sy[c][i] = Y[((size_t)(b * 64 + c)) * 1024 + n0 + i];
    }
    __syncthreads();
#pragma unroll
    for (int rep = 0; rep < 16; ++rep) {
        int idx = rep * 256 + tid;
        int i = idx >> 6, c = idx & 63;
        size_t gi = ((size_t)b * 1024 + n0 + i) * 64 + c;
        out[gi] = x[gi] + sy[c][i];
    }
}

// ---------------- K5: LN2 + lin1 + GELU -> H1 bf16 (B,N,256) ----------------
// block = 64 tokens; LN at staging (4 lanes/token); W1 staged in two 32KB
// LDS halves; register tile 8 tok x 4 ch per thread (ch = j*32 + cg).
__global__ __launch_bounds__(256) void k_leff1(const float* __restrict__ X1,
                                               const float* __restrict__ g2,
                                               const float* __restrict__ be2,
                                               const float* __restrict__ W1,
                                               const float* __restrict__ B1,
                                               unsigned short* __restrict__ H1b) {
    __shared__ float xs[64][65];
    __shared__ float w1s[64][128];
    int tid = threadIdx.x;
    size_t tok0 = (size_t)blockIdx.x * 64;
    // --- stage + LN: 4 lanes per token ---
    {
        int tok = tid >> 2, part = tid & 3;
        const float4* xp = (const float4*)(X1 + (tok0 + tok) * 64 + part * 16);
        float4 v0 = xp[0], v1 = xp[1], v2 = xp[2], v3 = xp[3];
        float s = v0.x + v0.y + v0.z + v0.w + v1.x + v1.y + v1.z + v1.w +
                  v2.x + v2.y + v2.z + v2.w + v3.x + v3.y + v3.z + v3.w;
        float ss = v0.x * v0.x + v0.y * v0.y + v0.z * v0.z + v0.w * v0.w +
                   v1.x * v1.x + v1.y * v1.y + v1.z * v1.z + v1.w * v1.w +
                   v2.x * v2.x + v2.y * v2.y + v2.z * v2.z + v2.w * v2.w +
                   v3.x * v3.x + v3.y * v3.y + v3.z * v3.z + v3.w * v3.w;
        s += __shfl_xor(s, 1, 64);
        ss += __shfl_xor(ss, 1, 64);
        s += __shfl_xor(s, 2, 64);
        ss += __shfl_xor(ss, 2, 64);
        float m = s * (1.f / 64.f);
        float var = ss * (1.f / 64.f) - m * m;
        float rstd = rsqrtf(var + 1e-5f);
        float vv[16] = {v0.x, v0.y, v0.z, v0.w, v1.x, v1.y, v1.z, v1.w,
                        v2.x, v2.y, v2.z, v2.w, v3.x, v3.y, v3.z, v3.w};
#pragma unroll
        for (int i = 0; i < 16; ++i) {
            int d = part * 16 + i;
            xs[tok][d] = (vv[i] - m) * rstd * g2[d] + be2[d];
        }
    }
    int tg = tid >> 5, cg = tid & 31;
#pragma unroll 1
    for (int half = 0; half < 2; ++half) {
        __syncthreads();
        // stage half of W1: w1s[d][c] = W1[d*256 + half*128 + c]
        for (int i = 0; i < 32; ++i) {
            int idx = i * 256 + tid;
            int d = idx >> 7, c = idx & 127;
            w1s[d][c] = W1[d * 256 + half * 128 + c];
        }
        __syncthreads();
        float acc[8][4];
#pragma unroll
        for (int t = 0; t < 8; ++t)
#pragma unroll
            for (int j = 0; j < 4; ++j)
                acc[t][j] = B1[half * 128 + j * 32 + cg];
#pragma unroll 2
        for (int d = 0; d < 64; ++d) {
            float w0 = w1s[d][cg];
            float w1v = w1s[d][32 + cg];
            float w2v = w1s[d][64 + cg];
            float w3v = w1s[d][96 + cg];
#pragma unroll
            for (int t = 0; t < 8; ++t) {
                float xv = xs[tg * 8 + t][d];
                acc[t][0] += xv * w0;
                acc[t][1] += xv * w1v;
                acc[t][2] += xv * w2v;
                acc[t][3] += xv * w3v;
            }
        }
#pragma unroll
        for (int t = 0; t < 8; ++t) {
            size_t base = (tok0 + tg * 8 + t) * 256 + half * 128 + cg;
#pragma unroll
            for (int j = 0; j < 4; ++j) {
                H1b[base + j * 32] = f2bf(gelu_exact(acc[t][j]));
            }
        }
    }
}

// ---------------- K6: dwconv3x3 + GELU + lin2 + bias + residual -> out ----------
// 2048 blocks x 128 threads; 1 lane/token (4-row strip); H1 tile in LDS;
// W2/DW/DB wave-uniform (loop-indexed only) -> scalar loads.
__global__ __launch_bounds__(128) void k_leff2(const unsigned short* __restrict__ H1b,
                                               const float* __restrict__ DW,
                                               const float* __restrict__ DB,
                                               const float* __restrict__ W2,
                                               const float* __restrict__ B2,
                                               float* __restrict__ out) {
    __shared__ float tile[32 * 205];
    int tid = threadIdx.x;
    int b = blockIdx.x >> 3;
    int strip = blockIdx.x & 7;
    int r = tid >> 5, w = tid & 31;
    int h_img = strip * 4 + r;

    float4 acc[16];
#pragma unroll
    for (int j = 0; j < 16; ++j) acc[j] = make_float4(0.f, 0.f, 0.f, 0.f);

    const float4* W2v = (const float4*)W2;  // row hid: 16 float4
#pragma unroll 1
    for (int cc = 0; cc < 8; ++cc) {
        __syncthreads();
        for (int idx = tid; idx < 6528; idx += 128) {
            int hid_l = idx & 31;
            int rest = idx >> 5;       // 0..203
            int tr = rest / 34;
            int wt = rest - tr * 34;
            int hr = strip * 4 - 1 + tr;
            int wi = wt - 1;
            float v = 0.f;
            if (hr >= 0 && hr < 32 && wi >= 0 && wi < 32)
                v = bf2f(H1b[((size_t)b * 1024 + hr * 32 + wi) * 256 + cc * 32 + hid_l]);
            tile[hid_l * 205 + rest] = v;
        }
        __syncthreads();
#pragma unroll 2
        for (int hl = 0; hl < 32; ++hl) {
            int hid = cc * 32 + hl;
            const float* tp = &tile[hl * 205 + r * 34 + w];
            float g = 0.f;
#pragma unroll
            for (int dr = 0; dr < 3; ++dr) {
#pragma unroll
                for (int dwx = 0; dwx < 3; ++dwx) {
                    g += tp[dr * 34 + dwx] * DW[hid * 9 + dr * 3 + dwx];
                }
            }
            g = gelu_exact(g + DB[hid]);
#pragma unroll
            for (int j = 0; j < 16; ++j) {
                float4 w4 = W2v[hid * 16 + j];
                acc[j].x += g * w4.x;
                acc[j].y += g * w4.y;
                acc[j].z += g * w4.z;
                acc[j].w += g * w4.w;
            }
        }
    }
    size_t tokg = (size_t)b * 1024 + h_img * 32 + w;
    const float4* B2v = (const float4*)B2;
    float4* outv = (float4*)(out + tokg * 64);
#pragma unroll
    for (int j = 0; j < 16; ++j) {
        float4 o = outv[j];
        float4 b4 = B2v[j];
        o.x += acc[j].x + b4.x;
        o.y += acc[j].y + b4.y;
        o.z += acc[j].z + b4.z;
        o.w += acc[j].w + b4.w;
        outv[j] = o;
    }
}

extern "C" void kernel_launch(void* const* d_in, const int* in_sizes, int n_in,
                              void* d_out, int out_size, void* d_ws, size_t ws_size,
                              hipStream_t stream) {
    const float* x = (const float*)d_in[0];
    const float* ln1_g = (const float*)d_in[1];
    const float* ln1_b = (const float*)d_in[2];
    const float* w_ll = (const float*)d_in[3];
    const float* w1 = (const float*)d_in[4];
    const float* w2 = (const float*)d_in[5];
    const float* b1 = (const float*)d_in[6];
    const float* b2 = (const float*)d_in[7];
    const float* ln2_g = (const float*)d_in[8];
    const float* ln2_b = (const float*)d_in[9];
    const float* lin1_w = (const float*)d_in[10];
    const float* lin1_b = (const float*)d_in[11];
    const float* dw_w = (const float*)d_in[12];
    const float* dw_b = (const float*)d_in[13];
    const float* lin2_w = (const float*)d_in[14];
    const float* lin2_b = (const float*)d_in[15];
    float* out = (float*)d_out;
    char* ws = (char*)d_ws;

    float* A = (float*)ws;
    float* HSr = (float*)(ws + 67108864);
    float* HSi = (float*)(ws + 167772160);
    float* LL = out;
    float* Y = A;
    unsigned short* H1b = (unsigned short*)ws;  // 134 MB; A/Y dead by then

    k_ln1_t<<<dim3(4096), dim3(256), 0, stream>>>(x, ln1_g, ln1_b, A);
    k_fwd<<<dim3(16384), dim3(256), 0, stream>>>(A, w_ll, LL, HSr, HSi);
    k_mlp<<<dim3(6144), dim3(256), 0, stream>>>(HSr, HSi, w1, w2, b1, b2);
    k_inv<<<dim3(16384), dim3(256), 0, stream>>>(LL, HSr, HSi, Y);
    k_addt<<<dim3(4096), dim3(256), 0, stream>>>(Y, x, out);
    k_leff1<<<dim3(4096), dim3(256), 0, stream>>>(out, ln2_g, ln2_b, lin1_w, lin1_b, H1b);
    k_leff2<<<dim3(2048), dim3(128), 0, stream>>>(H1b, dw_w, dw_b, lin2_w, lin2_b, out);
}

// Round 5
// 998.494 us; speedup vs baseline: 4.0141x; 1.3910x over previous
//
#include <hip/hip_runtime.h>
#include <math.h>

#define ISQ2 0.70710678118654752440f

typedef __attribute__((ext_vector_type(8))) short bfrag8;
typedef __attribute__((ext_vector_type(4))) float f32x4;

static __device__ __constant__ float H0c[13] = {
    -0.0017578f, 0.0f, 0.0222656f, -0.046875f, -0.0482422f, 0.296875f,
    0.5554688f, 0.296875f, -0.0482422f, -0.046875f, 0.0222656f, 0.0f, -0.0017578f};
static __device__ __constant__ float H1c[19] = {
    -7.06e-05f, 0.0f, 0.0013419f, -0.0018834f, -0.0071568f, 0.023856f,
    0.0556431f, -0.0516881f, -0.2997576f, 0.5594308f, -0.2997576f, -0.0516881f,
    0.0556431f, 0.023856f, -0.0071568f, -0.0018834f, 0.0013419f, 0.0f, -7.06e-05f};

__device__ __forceinline__ int refl32(int i) {
    if (i < 0) i = -1 - i;
    if (i > 31) i = 63 - i;
    return i;
}

__device__ __forceinline__ float gelu_exact(float x) {
    return 0.5f * x * (1.0f + erff(x * ISQ2));
}

__device__ __forceinline__ float bf2f(unsigned short u) {
    union { unsigned int i; float f; } v;
    v.i = ((unsigned int)u) << 16;
    return v.f;
}

__device__ __forceinline__ float bflo(unsigned int u) {
    union { unsigned int i; float f; } v;
    v.i = u << 16;
    return v.f;
}
__device__ __forceinline__ float bfhi(unsigned int u) {
    union { unsigned int i; float f; } v;
    v.i = u & 0xFFFF0000u;
    return v.f;
}

__device__ __forceinline__ unsigned short f2bf(float a) {
    union { float f; unsigned int i; } ua;
    ua.f = a;
    unsigned int r = ua.i + 0x7FFF + ((ua.i >> 16) & 1);
    return (unsigned short)(r >> 16);
}

// ---------------- K1: LN1 + transpose (B,N,C)->(B,C,32,32) ----------------
__global__ __launch_bounds__(256) void k_ln1_t(const float* __restrict__ x,
                                               const float* __restrict__ g,
                                               const float* __restrict__ be,
                                               float* __restrict__ A) {
    __shared__ float sx[64][65];
    __shared__ float rs[64][4], rq[64][4];
    __shared__ float sm[64], sv[64];
    int b = blockIdx.x >> 4;
    int n0 = (blockIdx.x & 15) << 6;
    int tid = threadIdx.x;
    const float* xp = x + ((size_t)b * 1024 + n0) * 64;
#pragma unroll
    for (int rep = 0; rep < 16; ++rep) {
        int idx = rep * 256 + tid;
        sx[idx >> 6][idx & 63] = xp[idx];
    }
    __syncthreads();
    {
        int i = tid >> 2, q = tid & 3;
        float s = 0.f, ss = 0.f;
#pragma unroll
        for (int d = 0; d < 16; ++d) {
            float v = sx[i][q * 16 + d];
            s += v; ss += v * v;
        }
        rs[i][q] = s; rq[i][q] = ss;
    }
    __syncthreads();
    if (tid < 64) {
        float s = rs[tid][0] + rs[tid][1] + rs[tid][2] + rs[tid][3];
        float ss = rq[tid][0] + rq[tid][1] + rq[tid][2] + rq[tid][3];
        float m = s * (1.f / 64.f);
        float v = ss * (1.f / 64.f) - m * m;
        sm[tid] = m;
        sv[tid] = rsqrtf(v + 1e-5f);
    }
    __syncthreads();
#pragma unroll
    for (int rep = 0; rep < 16; ++rep) {
        int idx = rep * 256 + tid;
        int c = idx >> 6, i = idx & 63;
        float val = (sx[i][c] - sm[i]) * sv[i] * g[c] + be[c];
        A[((size_t)(b * 64 + c)) * 1024 + n0 + i] = val;
    }
}

// ---------------- K2: forward DTCWT per (b,c) image ----------------
__device__ __forceinline__ float col19(const float (*arr)[33], int h, int w) {
    float s = 0.f;
#pragma unroll
    for (int k = 0; k < 19; ++k) s += H1c[k] * arr[refl32(h + k - 9)][w];
    return s;
}
__device__ __forceinline__ float col13(const float (*arr)[33], int h, int w) {
    float s = 0.f;
#pragma unroll
    for (int k = 0; k < 13; ++k) s += H0c[k] * arr[refl32(h + k - 6)][w];
    return s;
}

__global__ __launch_bounds__(256) void k_fwd(const float* __restrict__ A,
                                             const float* __restrict__ wll,
                                             float* __restrict__ LL,
                                             float* __restrict__ HSr,
                                             float* __restrict__ HSi) {
    __shared__ float sx[32][33], slo[32][33], shi[32][33];
    int bc = blockIdx.x;
    int c = bc & 63;
    int tid = threadIdx.x;
    const float* ap = A + (size_t)bc * 1024;
#pragma unroll
    for (int r = 0; r < 4; ++r) {
        int p = r * 256 + tid;
        sx[p >> 5][p & 31] = ap[p];
    }
    __syncthreads();
#pragma unroll
    for (int r = 0; r < 4; ++r) {
        int p = r * 256 + tid;
        int h = p >> 5, w = p & 31;
        float lo = 0.f, hi = 0.f;
#pragma unroll
        for (int k = 0; k < 13; ++k) lo += H0c[k] * sx[h][refl32(w + k - 6)];
#pragma unroll
        for (int k = 0; k < 19; ++k) hi += H1c[k] * sx[h][refl32(w + k - 9)];
        slo[h][w] = lo;
        shi[h][w] = hi;
    }
    __syncthreads();
#pragma unroll
    for (int r = 0; r < 4; ++r) {
        int p = r * 256 + tid;
        int h = p >> 5, w = p & 31;
        float acc = 0.f;
#pragma unroll
        for (int k = 0; k < 13; ++k) acc += H0c[k] * slo[refl32(h + k - 6)][w];
        LL[(size_t)bc * 1024 + p] = acc * wll[c * 1024 + p];
    }
    {
        int p = tid;
        int i = p >> 4, j = p & 15;
        int h0 = 2 * i, w0 = 2 * j;
        size_t base = (size_t)bc * 1536 + p;
        float a, bb, cc, dd;
        a = col19(slo, h0, w0); bb = col19(slo, h0, w0 + 1);
        cc = col19(slo, h0 + 1, w0); dd = col19(slo, h0 + 1, w0 + 1);
        HSr[base + 0 * 256] = (a - dd) * ISQ2; HSi[base + 0 * 256] = (bb + cc) * ISQ2;
        HSr[base + 5 * 256] = (a + dd) * ISQ2; HSi[base + 5 * 256] = (bb - cc) * ISQ2;
        a = col19(shi, h0, w0); bb = col19(shi, h0, w0 + 1);
        cc = col19(shi, h0 + 1, w0); dd = col19(shi, h0 + 1, w0 + 1);
        HSr[base + 1 * 256] = (a - dd) * ISQ2; HSi[base + 1 * 256] = (bb + cc) * ISQ2;
        HSr[base + 4 * 256] = (a + dd) * ISQ2; HSi[base + 4 * 256] = (bb - cc) * ISQ2;
        a = col13(shi, h0, w0); bb = col13(shi, h0, w0 + 1);
        cc = col13(shi, h0 + 1, w0); dd = col13(shi, h0 + 1, w0 + 1);
        HSr[base + 2 * 256] = (a - dd) * ISQ2; HSi[base + 2 * 256] = (bb + cc) * ISQ2;
        HSr[base + 3 * 256] = (a + dd) * ISQ2; HSi[base + 3 * 256] = (bb - cc) * ISQ2;
    }
}

// ---------------- K3: complex block-diagonal MLP (in-place on HS) ----------------
__global__ __launch_bounds__(256) void k_mlp(float* __restrict__ HSr,
                                             float* __restrict__ HSi,
                                             const float* __restrict__ w1,
                                             const float* __restrict__ w2,
                                             const float* __restrict__ b1,
                                             const float* __restrict__ b2) {
    __shared__ float sr[64][65], si[64][65];
    __shared__ float w1s[2048], w2s[2048], b1s[128], b2s[128];
    int blk = blockIdx.x;
    int b = blk / 24;
    int rem = blk % 24;
    int o = rem >> 2;
    int ij0 = (rem & 3) << 6;
    int tid = threadIdx.x;
    for (int idx = tid; idx < 2048; idx += 256) {
        w1s[idx] = w1[idx];
        w2s[idx] = w2[idx];
    }
    if (tid < 128) { b1s[tid] = b1[tid]; b2s[tid] = b2[tid]; }
#pragma unroll
    for (int rep = 0; rep < 16; ++rep) {
        int idx = rep * 256 + tid;
        int c = idx >> 6, j = idx & 63;
        size_t gi = ((size_t)(b * 64 + c) * 6 + o) * 256 + ij0 + j;
        sr[c][j] = HSr[gi];
        si[c][j] = HSi[gi];
    }
    __syncthreads();
    {
        int j = tid & 63, q = tid >> 6;
        float xr[16], xi[16];
#pragma unroll
        for (int d = 0; d < 16; ++d) {
            xr[d] = sr[q * 16 + d][j];
            xi[d] = si[q * 16 + d][j];
        }
        float r1[16], i1[16];
#pragma unroll
        for (int k = 0; k < 16; ++k) {
            float ar = b1s[q * 16 + k];
            float ai = b1s[64 + q * 16 + k];
#pragma unroll
            for (int d = 0; d < 16; ++d) {
                float wr = w1s[q * 256 + d * 16 + k];
                float wi = w1s[1024 + q * 256 + d * 16 + k];
                ar += xr[d] * wr - xi[d] * wi;
                ai += xr[d] * wi + xi[d] * wr;
            }
            r1[k] = fmaxf(ar, 0.f);
            i1[k] = fmaxf(ai, 0.f);
        }
#pragma unroll
        for (int k = 0; k < 16; ++k) {
            float ar = b2s[q * 16 + k];
            float ai = b2s[64 + q * 16 + k];
#pragma unroll
            for (int d = 0; d < 16; ++d) {
                float wr = w2s[q * 256 + d * 16 + k];
                float wi = w2s[1024 + q * 256 + d * 16 + k];
                ar += r1[d] * wr - i1[d] * wi;
                ai += r1[d] * wi + i1[d] * wr;
            }
            sr[q * 16 + k][j] = ar;
            si[q * 16 + k][j] = ai;
        }
    }
    __syncthreads();
#pragma unroll
    for (int rep = 0; rep < 16; ++rep) {
        int idx = rep * 256 + tid;
        int c = idx >> 6, j = idx & 63;
        size_t gi = ((size_t)(b * 64 + c) * 6 + o) * 256 + ij0 + j;
        HSr[gi] = sr[c][j];
        HSi[gi] = si[c][j];
    }
}

// ---------------- K4: inverse DTCWT per (b,c) -> Y (B,C,N) ----------------
__global__ __launch_bounds__(256) void k_inv(const float* __restrict__ LL,
                                             const float* __restrict__ HSr,
                                             const float* __restrict__ HSi,
                                             float* __restrict__ Y) {
    __shared__ float sll[32][33], slh[32][33], shl[32][33], shh[32][33];
    __shared__ float slo[32][33], shi[32][33];
    int bc = blockIdx.x;
    int tid = threadIdx.x;
    const float* lp = LL + (size_t)bc * 1024;
#pragma unroll
    for (int r = 0; r < 4; ++r) {
        int p = r * 256 + tid;
        sll[p >> 5][p & 31] = lp[p];
    }
    {
        int p = tid;
        int i = p >> 4, j = p & 15;
        int h0 = 2 * i, w0 = 2 * j;
        size_t base = (size_t)bc * 1536 + p;
        float o0r = HSr[base + 0 * 256], o0i = HSi[base + 0 * 256];
        float o1r = HSr[base + 1 * 256], o1i = HSi[base + 1 * 256];
        float o2r = HSr[base + 2 * 256], o2i = HSi[base + 2 * 256];
        float o3r = HSr[base + 3 * 256], o3i = HSi[base + 3 * 256];
        float o4r = HSr[base + 4 * 256], o4i = HSi[base + 4 * 256];
        float o5r = HSr[base + 5 * 256], o5i = HSi[base + 5 * 256];
        slh[h0][w0] = (o0r + o5r) * ISQ2;
        slh[h0][w0 + 1] = (o0i + o5i) * ISQ2;
        slh[h0 + 1][w0] = (o0i - o5i) * ISQ2;
        slh[h0 + 1][w0 + 1] = (o5r - o0r) * ISQ2;
        shl[h0][w0] = (o2r + o3r) * ISQ2;
        shl[h0][w0 + 1] = (o2i + o3i) * ISQ2;
        shl[h0 + 1][w0] = (o2i - o3i) * ISQ2;
        shl[h0 + 1][w0 + 1] = (o3r - o2r) * ISQ2;
        shh[h0][w0] = (o1r + o4r) * ISQ2;
        shh[h0][w0 + 1] = (o1i + o4i) * ISQ2;
        shh[h0 + 1][w0] = (o1i - o4i) * ISQ2;
        shh[h0 + 1][w0 + 1] = (o4r - o1r) * ISQ2;
    }
    __syncthreads();
#pragma unroll
    for (int r = 0; r < 4; ++r) {
        int p = r * 256 + tid;
        int h = p >> 5, w = p & 31;
        float lo = 0.f, hi = 0.f;
#pragma unroll
        for (int k = 0; k < 19; ++k) {
            float g0 = (k & 1) ? H1c[k] : -H1c[k];
            int hh2 = refl32(h + k - 9);
            lo += g0 * sll[hh2][w];
            hi += g0 * shl[hh2][w];
        }
#pragma unroll
        for (int k = 0; k < 13; ++k) {
            float g1 = (k & 1) ? H0c[k] : -H0c[k];
            int hh2 = refl32(h + k - 6);
            lo += g1 * slh[hh2][w];
            hi += g1 * shh[hh2][w];
        }
        slo[h][w] = lo;
        shi[h][w] = hi;
    }
    __syncthreads();
#pragma unroll
    for (int r = 0; r < 4; ++r) {
        int p = r * 256 + tid;
        int h = p >> 5, w = p & 31;
        float y = 0.f;
#pragma unroll
        for (int k = 0; k < 19; ++k) {
            float g0 = (k & 1) ? H1c[k] : -H1c[k];
            y += g0 * slo[h][refl32(w + k - 9)];
        }
#pragma unroll
        for (int k = 0; k < 13; ++k) {
            float g1 = (k & 1) ? H0c[k] : -H0c[k];
            y += g1 * shi[h][refl32(w + k - 6)];
        }
        Y[(size_t)bc * 1024 + p] = y;
    }
}

// ---------------- K4b: X1 = x + Y^T -> d_out (B,N,C) ----------------
__global__ __launch_bounds__(256) void k_addt(const float* __restrict__ Y,
                                              const float* __restrict__ x,
                                              float* __restrict__ out) {
    __shared__ float sy[64][65];
    int b = blockIdx.x >> 4;
    int n0 = (blockIdx.x & 15) << 6;
    int tid = threadIdx.x;
#pragma unroll
    for (int rep = 0; rep < 16; ++rep) {
        int idx = rep * 256 + tid;
        int c = idx >> 6, i = idx & 63;
        sy[c][i] = Y[((size_t)(b * 64 + c)) * 1024 + n0 + i];
    }
    __syncthreads();
#pragma unroll
    for (int rep = 0; rep < 16; ++rep) {
        int idx = rep * 256 + tid;
        int i = idx >> 6, c = idx & 63;
        size_t gi = ((size_t)b * 1024 + n0 + i) * 64 + c;
        out[gi] = x[gi] + sy[c][i];
    }
}

// ---------------- K5: LN2 + lin1 + GELU -> H1 bf16 (B,N,256) ----------------
__global__ __launch_bounds__(256) void k_leff1(const float* __restrict__ X1,
                                               const float* __restrict__ g2,
                                               const float* __restrict__ be2,
                                               const float* __restrict__ W1,
                                               const float* __restrict__ B1,
                                               unsigned short* __restrict__ H1b) {
    __shared__ float xs[64][65];
    __shared__ float w1s[64][128];
    int tid = threadIdx.x;
    size_t tok0 = (size_t)blockIdx.x * 64;
    {
        int tok = tid >> 2, part = tid & 3;
        const float4* xp = (const float4*)(X1 + (tok0 + tok) * 64 + part * 16);
        float4 v0 = xp[0], v1 = xp[1], v2 = xp[2], v3 = xp[3];
        float s = v0.x + v0.y + v0.z + v0.w + v1.x + v1.y + v1.z + v1.w +
                  v2.x + v2.y + v2.z + v2.w + v3.x + v3.y + v3.z + v3.w;
        float ss = v0.x * v0.x + v0.y * v0.y + v0.z * v0.z + v0.w * v0.w +
                   v1.x * v1.x + v1.y * v1.y + v1.z * v1.z + v1.w * v1.w +
                   v2.x * v2.x + v2.y * v2.y + v2.z * v2.z + v2.w * v2.w +
                   v3.x * v3.x + v3.y * v3.y + v3.z * v3.z + v3.w * v3.w;
        s += __shfl_xor(s, 1, 64);
        ss += __shfl_xor(ss, 1, 64);
        s += __shfl_xor(s, 2, 64);
        ss += __shfl_xor(ss, 2, 64);
        float m = s * (1.f / 64.f);
        float var = ss * (1.f / 64.f) - m * m;
        float rstd = rsqrtf(var + 1e-5f);
        float vv[16] = {v0.x, v0.y, v0.z, v0.w, v1.x, v1.y, v1.z, v1.w,
                        v2.x, v2.y, v2.z, v2.w, v3.x, v3.y, v3.z, v3.w};
#pragma unroll
        for (int i = 0; i < 16; ++i) {
            int d = part * 16 + i;
            xs[tok][d] = (vv[i] - m) * rstd * g2[d] + be2[d];
        }
    }
    int tg = tid >> 5, cg = tid & 31;
#pragma unroll 1
    for (int half = 0; half < 2; ++half) {
        __syncthreads();
        for (int i = 0; i < 32; ++i) {
            int idx = i * 256 + tid;
            int d = idx >> 7, c = idx & 127;
            w1s[d][c] = W1[d * 256 + half * 128 + c];
        }
        __syncthreads();
        float acc[8][4];
#pragma unroll
        for (int t = 0; t < 8; ++t)
#pragma unroll
            for (int j = 0; j < 4; ++j)
                acc[t][j] = B1[half * 128 + j * 32 + cg];
#pragma unroll 2
        for (int d = 0; d < 64; ++d) {
            float w0 = w1s[d][cg];
            float w1v = w1s[d][32 + cg];
            float w2v = w1s[d][64 + cg];
            float w3v = w1s[d][96 + cg];
#pragma unroll
            for (int t = 0; t < 8; ++t) {
                float xv = xs[tg * 8 + t][d];
                acc[t][0] += xv * w0;
                acc[t][1] += xv * w1v;
                acc[t][2] += xv * w2v;
                acc[t][3] += xv * w3v;
            }
        }
#pragma unroll
        for (int t = 0; t < 8; ++t) {
            size_t base = (tok0 + tg * 8 + t) * 256 + half * 128 + cg;
#pragma unroll
            for (int j = 0; j < 4; ++j) {
                H1b[base + j * 32] = f2bf(gelu_exact(acc[t][j]));
            }
        }
    }
}

// ---------------- K5b: prep DWT (tap-major) + W2T bf16 ----------------
__global__ __launch_bounds__(256) void k_prep(const float* __restrict__ DW,
                                              const float* __restrict__ W2,
                                              float* __restrict__ DWT,
                                              unsigned short* __restrict__ W2T) {
    int tid = threadIdx.x;
    for (int i = tid; i < 2304; i += 256) {
        int hid = i / 9, t = i - hid * 9;
        DWT[t * 256 + hid] = DW[i];
    }
    for (int i = tid; i < 16384; i += 256) {
        int n = i >> 8, k = i & 255;
        W2T[i] = f2bf(W2[k * 64 + n]);
    }
}

// ---------------- K6: fused dwconv3x3+GELU+lin2(MFMA)+bias+residual ----------
// 1 wave = one 16-token M-tile (half image row). Per K-step (32 hid):
// each lane computes its 8 A-frag values (9-tap conv from global bf16 H1,
// fp32 weights, +DB, exact GELU), packs bf16, MFMA against bf16 W2T.
__global__ __launch_bounds__(256) void k_leff2m(const unsigned short* __restrict__ H1b,
                                                const float* __restrict__ DWT,
                                                const float* __restrict__ DB,
                                                const unsigned short* __restrict__ W2T,
                                                const float* __restrict__ B2,
                                                float* __restrict__ out) {
    int tid = threadIdx.x;
    int wid = tid >> 6, lane = tid & 63;
    int mt = blockIdx.x * 4 + wid;   // 0..16383
    int b = mt >> 6;
    int rem = mt & 63;
    int h = rem >> 1;                // image row (wave-uniform)
    int w0 = (rem & 1) << 4;         // 0 or 16
    int lr = lane & 15;              // A-row (token) / C-col index
    int kg = lane >> 4;              // k-group 0..3
    int wA = w0 + lr;                // this lane's token w

    f32x4 acc[4];
#pragma unroll
    for (int n = 0; n < 4; ++n) acc[n] = (f32x4){0.f, 0.f, 0.f, 0.f};

    size_t rowbase = (size_t)b * 1024 + (size_t)h * 32;

#pragma unroll 1
    for (int k0 = 0; k0 < 8; ++k0) {
        int hid0 = k0 * 32 + kg * 8;
        const f32x4* dbp = (const f32x4*)(DB + hid0);
        f32x4 d0 = dbp[0], d1 = dbp[1];
        float cv[8] = {d0.x, d0.y, d0.z, d0.w, d1.x, d1.y, d1.z, d1.w};
#pragma unroll
        for (int dr = -1; dr <= 1; ++dr) {
            int hr = h + dr;
            if (hr < 0 || hr > 31) continue;   // wave-uniform
#pragma unroll
            for (int dc = -1; dc <= 1; ++dc) {
                int wc = wA + dc;
                if (wc < 0 || wc > 31) continue;  // edge lanes only
                uint4 v = *(const uint4*)(H1b + (rowbase + dr * 32 + wc) * 256 + hid0);
                const f32x4* wp = (const f32x4*)(DWT + ((dr + 1) * 3 + (dc + 1)) * 256 + hid0);
                f32x4 q0 = wp[0], q1 = wp[1];
                cv[0] += bflo(v.x) * q0.x;
                cv[1] += bfhi(v.x) * q0.y;
                cv[2] += bflo(v.y) * q0.z;
                cv[3] += bfhi(v.y) * q0.w;
                cv[4] += bflo(v.z) * q1.x;
                cv[5] += bfhi(v.z) * q1.y;
                cv[6] += bflo(v.w) * q1.z;
                cv[7] += bfhi(v.w) * q1.w;
            }
        }
        bfrag8 a;
#pragma unroll
        for (int e = 0; e < 8; ++e) a[e] = (short)f2bf(gelu_exact(cv[e]));
#pragma unroll
        for (int n = 0; n < 4; ++n) {
            bfrag8 bf = *(const bfrag8*)(W2T + ((size_t)(n * 16 + lr) * 256 + k0 * 32 + kg * 8));
            acc[n] = __builtin_amdgcn_mfma_f32_16x16x32_bf16(a, bf, acc[n], 0, 0, 0);
        }
    }
    // epilogue: C layout col=lane&15, row=(lane>>4)*4+reg
#pragma unroll
    for (int n = 0; n < 4; ++n) {
        int c = n * 16 + lr;
        float b2v = B2[c];
#pragma unroll
        for (int reg = 0; reg < 4; ++reg) {
            int rowTok = w0 + kg * 4 + reg;
            size_t gi = (rowbase + rowTok) * 64 + c;
            out[gi] += acc[n][reg] + b2v;
        }
    }
}

extern "C" void kernel_launch(void* const* d_in, const int* in_sizes, int n_in,
                              void* d_out, int out_size, void* d_ws, size_t ws_size,
                              hipStream_t stream) {
    const float* x = (const float*)d_in[0];
    const float* ln1_g = (const float*)d_in[1];
    const float* ln1_b = (const float*)d_in[2];
    const float* w_ll = (const float*)d_in[3];
    const float* w1 = (const float*)d_in[4];
    const float* w2 = (const float*)d_in[5];
    const float* b1 = (const float*)d_in[6];
    const float* b2 = (const float*)d_in[7];
    const float* ln2_g = (const float*)d_in[8];
    const float* ln2_b = (const float*)d_in[9];
    const float* lin1_w = (const float*)d_in[10];
    const float* lin1_b = (const float*)d_in[11];
    const float* dw_w = (const float*)d_in[12];
    const float* dw_b = (const float*)d_in[13];
    const float* lin2_w = (const float*)d_in[14];
    const float* lin2_b = (const float*)d_in[15];
    float* out = (float*)d_out;
    char* ws = (char*)d_ws;

    float* A = (float*)ws;
    float* HSr = (float*)(ws + 67108864);
    float* HSi = (float*)(ws + 167772160);
    float* LL = out;
    float* Y = A;
    unsigned short* H1b = (unsigned short*)ws;          // [0, 134.2MB)
    float* DWT = (float*)(ws + 167772160);              // reuses dead HSi
    unsigned short* W2T = (unsigned short*)(ws + 167772160 + 16384);

    k_ln1_t<<<dim3(4096), dim3(256), 0, stream>>>(x, ln1_g, ln1_b, A);
    k_fwd<<<dim3(16384), dim3(256), 0, stream>>>(A, w_ll, LL, HSr, HSi);
    k_mlp<<<dim3(6144), dim3(256), 0, stream>>>(HSr, HSi, w1, w2, b1, b2);
    k_inv<<<dim3(16384), dim3(256), 0, stream>>>(LL, HSr, HSi, Y);
    k_addt<<<dim3(4096), dim3(256), 0, stream>>>(Y, x, out);
    k_prep<<<dim3(1), dim3(256), 0, stream>>>(dw_w, lin2_w, DWT, W2T);
    k_leff1<<<dim3(4096), dim3(256), 0, stream>>>(out, ln2_g, ln2_b, lin1_w, lin1_b, H1b);
    k_leff2m<<<dim3(4096), dim3(256), 0, stream>>>(H1b, DWT, dw_b, W2T, b2, out);
}

// Round 6
// 948.646 us; speedup vs baseline: 4.2251x; 1.0525x over previous
//
#include <hip/hip_runtime.h>
#include <math.h>

#define ISQ2 0.70710678118654752440f

typedef __attribute__((ext_vector_type(8))) short bfrag8;
typedef __attribute__((ext_vector_type(4))) float f32x4;

static __device__ __constant__ float H0c[13] = {
    -0.0017578f, 0.0f, 0.0222656f, -0.046875f, -0.0482422f, 0.296875f,
    0.5554688f, 0.296875f, -0.0482422f, -0.046875f, 0.0222656f, 0.0f, -0.0017578f};
static __device__ __constant__ float H1c[19] = {
    -7.06e-05f, 0.0f, 0.0013419f, -0.0018834f, -0.0071568f, 0.023856f,
    0.0556431f, -0.0516881f, -0.2997576f, 0.5594308f, -0.2997576f, -0.0516881f,
    0.0556431f, 0.023856f, -0.0071568f, -0.0018834f, 0.0013419f, 0.0f, -7.06e-05f};

__device__ __forceinline__ int refl32(int i) {
    if (i < 0) i = -1 - i;
    if (i > 31) i = 63 - i;
    return i;
}

__device__ __forceinline__ float gelu_exact(float x) {
    return 0.5f * x * (1.0f + erff(x * ISQ2));
}

__device__ __forceinline__ float bf2f(unsigned short u) {
    union { unsigned int i; float f; } v;
    v.i = ((unsigned int)u) << 16;
    return v.f;
}

__device__ __forceinline__ float bflo(unsigned int u) {
    union { unsigned int i; float f; } v;
    v.i = u << 16;
    return v.f;
}
__device__ __forceinline__ float bfhi(unsigned int u) {
    union { unsigned int i; float f; } v;
    v.i = u & 0xFFFF0000u;
    return v.f;
}

__device__ __forceinline__ unsigned short f2bf(float a) {
    union { float f; unsigned int i; } ua;
    ua.f = a;
    unsigned int r = ua.i + 0x7FFF + ((ua.i >> 16) & 1);
    return (unsigned short)(r >> 16);
}

// ---------------- K1: LN1 + transpose (B,N,C)->(B,C,32,32) ----------------
__global__ __launch_bounds__(256) void k_ln1_t(const float* __restrict__ x,
                                               const float* __restrict__ g,
                                               const float* __restrict__ be,
                                               float* __restrict__ A) {
    __shared__ float sx[64][65];
    __shared__ float rs[64][4], rq[64][4];
    __shared__ float sm[64], sv[64];
    int b = blockIdx.x >> 4;
    int n0 = (blockIdx.x & 15) << 6;
    int tid = threadIdx.x;
    const float* xp = x + ((size_t)b * 1024 + n0) * 64;
#pragma unroll
    for (int rep = 0; rep < 16; ++rep) {
        int idx = rep * 256 + tid;
        sx[idx >> 6][idx & 63] = xp[idx];
    }
    __syncthreads();
    {
        int i = tid >> 2, q = tid & 3;
        float s = 0.f, ss = 0.f;
#pragma unroll
        for (int d = 0; d < 16; ++d) {
            float v = sx[i][q * 16 + d];
            s += v; ss += v * v;
        }
        rs[i][q] = s; rq[i][q] = ss;
    }
    __syncthreads();
    if (tid < 64) {
        float s = rs[tid][0] + rs[tid][1] + rs[tid][2] + rs[tid][3];
        float ss = rq[tid][0] + rq[tid][1] + rq[tid][2] + rq[tid][3];
        float m = s * (1.f / 64.f);
        float v = ss * (1.f / 64.f) - m * m;
        sm[tid] = m;
        sv[tid] = rsqrtf(v + 1e-5f);
    }
    __syncthreads();
#pragma unroll
    for (int rep = 0; rep < 16; ++rep) {
        int idx = rep * 256 + tid;
        int c = idx >> 6, i = idx & 63;
        float val = (sx[i][c] - sm[i]) * sv[i] * g[c] + be[c];
        A[((size_t)(b * 64 + c)) * 1024 + n0 + i] = val;
    }
}

// ---------------- K2: forward DTCWT per (b,c) image ----------------
__device__ __forceinline__ float col19(const float (*arr)[33], int h, int w) {
    float s = 0.f;
#pragma unroll
    for (int k = 0; k < 19; ++k) s += H1c[k] * arr[refl32(h + k - 9)][w];
    return s;
}
__device__ __forceinline__ float col13(const float (*arr)[33], int h, int w) {
    float s = 0.f;
#pragma unroll
    for (int k = 0; k < 13; ++k) s += H0c[k] * arr[refl32(h + k - 6)][w];
    return s;
}

__global__ __launch_bounds__(256) void k_fwd(const float* __restrict__ A,
                                             const float* __restrict__ wll,
                                             float* __restrict__ LL,
                                             float* __restrict__ HSr,
                                             float* __restrict__ HSi) {
    __shared__ float sx[32][33], slo[32][33], shi[32][33];
    int bc = blockIdx.x;
    int c = bc & 63;
    int tid = threadIdx.x;
    const float* ap = A + (size_t)bc * 1024;
#pragma unroll
    for (int r = 0; r < 4; ++r) {
        int p = r * 256 + tid;
        sx[p >> 5][p & 31] = ap[p];
    }
    __syncthreads();
#pragma unroll
    for (int r = 0; r < 4; ++r) {
        int p = r * 256 + tid;
        int h = p >> 5, w = p & 31;
        float lo = 0.f, hi = 0.f;
#pragma unroll
        for (int k = 0; k < 13; ++k) lo += H0c[k] * sx[h][refl32(w + k - 6)];
#pragma unroll
        for (int k = 0; k < 19; ++k) hi += H1c[k] * sx[h][refl32(w + k - 9)];
        slo[h][w] = lo;
        shi[h][w] = hi;
    }
    __syncthreads();
#pragma unroll
    for (int r = 0; r < 4; ++r) {
        int p = r * 256 + tid;
        int h = p >> 5, w = p & 31;
        float acc = 0.f;
#pragma unroll
        for (int k = 0; k < 13; ++k) acc += H0c[k] * slo[refl32(h + k - 6)][w];
        LL[(size_t)bc * 1024 + p] = acc * wll[c * 1024 + p];
    }
    {
        int p = tid;
        int i = p >> 4, j = p & 15;
        int h0 = 2 * i, w0 = 2 * j;
        size_t base = (size_t)bc * 1536 + p;
        float a, bb, cc, dd;
        a = col19(slo, h0, w0); bb = col19(slo, h0, w0 + 1);
        cc = col19(slo, h0 + 1, w0); dd = col19(slo, h0 + 1, w0 + 1);
        HSr[base + 0 * 256] = (a - dd) * ISQ2; HSi[base + 0 * 256] = (bb + cc) * ISQ2;
        HSr[base + 5 * 256] = (a + dd) * ISQ2; HSi[base + 5 * 256] = (bb - cc) * ISQ2;
        a = col19(shi, h0, w0); bb = col19(shi, h0, w0 + 1);
        cc = col19(shi, h0 + 1, w0); dd = col19(shi, h0 + 1, w0 + 1);
        HSr[base + 1 * 256] = (a - dd) * ISQ2; HSi[base + 1 * 256] = (bb + cc) * ISQ2;
        HSr[base + 4 * 256] = (a + dd) * ISQ2; HSi[base + 4 * 256] = (bb - cc) * ISQ2;
        a = col13(shi, h0, w0); bb = col13(shi, h0, w0 + 1);
        cc = col13(shi, h0 + 1, w0); dd = col13(shi, h0 + 1, w0 + 1);
        HSr[base + 2 * 256] = (a - dd) * ISQ2; HSi[base + 2 * 256] = (bb + cc) * ISQ2;
        HSr[base + 3 * 256] = (a + dd) * ISQ2; HSi[base + 3 * 256] = (bb - cc) * ISQ2;
    }
}

// ---------------- K3: complex block-diagonal MLP (token-per-lane, scalar weights) --
// 1536 blocks = (b, o); lane = ij token. Weights loop-indexed only -> s_load.
__global__ __launch_bounds__(256) void k_mlp(float* __restrict__ HSr,
                                             float* __restrict__ HSi,
                                             const float* __restrict__ w1,
                                             const float* __restrict__ w2,
                                             const float* __restrict__ b1,
                                             const float* __restrict__ b2) {
    int tid = threadIdx.x;
    int b = blockIdx.x / 6;
    int o = blockIdx.x - b * 6;
    size_t base = ((size_t)b * 384 + o) * 256 + tid;  // c=0 element for this lane
#pragma unroll 1
    for (int q = 0; q < 4; ++q) {
        float xr[16], xi[16];
#pragma unroll
        for (int d = 0; d < 16; ++d) {
            size_t gi = base + (size_t)(q * 16 + d) * 1536;
            xr[d] = HSr[gi];
            xi[d] = HSi[gi];
        }
        float r1[16], i1[16];
#pragma unroll 4
        for (int k = 0; k < 16; ++k) {
            float ar = b1[q * 16 + k];
            float ai = b1[64 + q * 16 + k];
#pragma unroll
            for (int d = 0; d < 16; ++d) {
                float wr = w1[q * 256 + d * 16 + k];
                float wi = w1[1024 + q * 256 + d * 16 + k];
                ar += xr[d] * wr - xi[d] * wi;
                ai += xr[d] * wi + xi[d] * wr;
            }
            r1[k] = fmaxf(ar, 0.f);
            i1[k] = fmaxf(ai, 0.f);
        }
#pragma unroll 4
        for (int k = 0; k < 16; ++k) {
            float ar = b2[q * 16 + k];
            float ai = b2[64 + q * 16 + k];
#pragma unroll
            for (int d = 0; d < 16; ++d) {
                float wr = w2[q * 256 + d * 16 + k];
                float wi = w2[1024 + q * 256 + d * 16 + k];
                ar += r1[d] * wr - i1[d] * wi;
                ai += r1[d] * wi + i1[d] * wr;
            }
            size_t gi = base + (size_t)(q * 16 + k) * 1536;
            HSr[gi] = ar;
            HSi[gi] = ai;
        }
    }
}

// ---------------- K4: inverse DTCWT per (b,c) -> Y (B,C,N) ----------------
__global__ __launch_bounds__(256) void k_inv(const float* __restrict__ LL,
                                             const float* __restrict__ HSr,
                                             const float* __restrict__ HSi,
                                             float* __restrict__ Y) {
    __shared__ float sll[32][33], slh[32][33], shl[32][33], shh[32][33];
    __shared__ float slo[32][33], shi[32][33];
    int bc = blockIdx.x;
    int tid = threadIdx.x;
    const float* lp = LL + (size_t)bc * 1024;
#pragma unroll
    for (int r = 0; r < 4; ++r) {
        int p = r * 256 + tid;
        sll[p >> 5][p & 31] = lp[p];
    }
    {
        int p = tid;
        int i = p >> 4, j = p & 15;
        int h0 = 2 * i, w0 = 2 * j;
        size_t base = (size_t)bc * 1536 + p;
        float o0r = HSr[base + 0 * 256], o0i = HSi[base + 0 * 256];
        float o1r = HSr[base + 1 * 256], o1i = HSi[base + 1 * 256];
        float o2r = HSr[base + 2 * 256], o2i = HSi[base + 2 * 256];
        float o3r = HSr[base + 3 * 256], o3i = HSi[base + 3 * 256];
        float o4r = HSr[base + 4 * 256], o4i = HSi[base + 4 * 256];
        float o5r = HSr[base + 5 * 256], o5i = HSi[base + 5 * 256];
        slh[h0][w0] = (o0r + o5r) * ISQ2;
        slh[h0][w0 + 1] = (o0i + o5i) * ISQ2;
        slh[h0 + 1][w0] = (o0i - o5i) * ISQ2;
        slh[h0 + 1][w0 + 1] = (o5r - o0r) * ISQ2;
        shl[h0][w0] = (o2r + o3r) * ISQ2;
        shl[h0][w0 + 1] = (o2i + o3i) * ISQ2;
        shl[h0 + 1][w0] = (o2i - o3i) * ISQ2;
        shl[h0 + 1][w0 + 1] = (o3r - o2r) * ISQ2;
        shh[h0][w0] = (o1r + o4r) * ISQ2;
        shh[h0][w0 + 1] = (o1i + o4i) * ISQ2;
        shh[h0 + 1][w0] = (o1i - o4i) * ISQ2;
        shh[h0 + 1][w0 + 1] = (o4r - o1r) * ISQ2;
    }
    __syncthreads();
#pragma unroll
    for (int r = 0; r < 4; ++r) {
        int p = r * 256 + tid;
        int h = p >> 5, w = p & 31;
        float lo = 0.f, hi = 0.f;
#pragma unroll
        for (int k = 0; k < 19; ++k) {
            float g0 = (k & 1) ? H1c[k] : -H1c[k];
            int hh2 = refl32(h + k - 9);
            lo += g0 * sll[hh2][w];
            hi += g0 * shl[hh2][w];
        }
#pragma unroll
        for (int k = 0; k < 13; ++k) {
            float g1 = (k & 1) ? H0c[k] : -H0c[k];
            int hh2 = refl32(h + k - 6);
            lo += g1 * slh[hh2][w];
            hi += g1 * shh[hh2][w];
        }
        slo[h][w] = lo;
        shi[h][w] = hi;
    }
    __syncthreads();
#pragma unroll
    for (int r = 0; r < 4; ++r) {
        int p = r * 256 + tid;
        int h = p >> 5, w = p & 31;
        float y = 0.f;
#pragma unroll
        for (int k = 0; k < 19; ++k) {
            float g0 = (k & 1) ? H1c[k] : -H1c[k];
            y += g0 * slo[h][refl32(w + k - 9)];
        }
#pragma unroll
        for (int k = 0; k < 13; ++k) {
            float g1 = (k & 1) ? H0c[k] : -H0c[k];
            y += g1 * shi[h][refl32(w + k - 6)];
        }
        Y[(size_t)bc * 1024 + p] = y;
    }
}

// ---------------- K4b: X1 = x + Y^T -> d_out (B,N,C) ----------------
__global__ __launch_bounds__(256) void k_addt(const float* __restrict__ Y,
                                              const float* __restrict__ x,
                                              float* __restrict__ out) {
    __shared__ float sy[64][65];
    int b = blockIdx.x >> 4;
    int n0 = (blockIdx.x & 15) << 6;
    int tid = threadIdx.x;
#pragma unroll
    for (int rep = 0; rep < 16; ++rep) {
        int idx = rep * 256 + tid;
        int c = idx >> 6, i = idx & 63;
        sy[c][i] = Y[((size_t)(b * 64 + c)) * 1024 + n0 + i];
    }
    __syncthreads();
#pragma unroll
    for (int rep = 0; rep < 16; ++rep) {
        int idx = rep * 256 + tid;
        int i = idx >> 6, c = idx & 63;
        size_t gi = ((size_t)b * 1024 + n0 + i) * 64 + c;
        out[gi] = x[gi] + sy[c][i];
    }
}

// ---------------- K5: LN2 + lin1 + GELU -> H1 bf16 chunk-major ----------------
// H1 layout: (b, k0=hid/32, h, w, hid%32)
__global__ __launch_bounds__(256) void k_leff1(const float* __restrict__ X1,
                                               const float* __restrict__ g2,
                                               const float* __restrict__ be2,
                                               const float* __restrict__ W1,
                                               const float* __restrict__ B1,
                                               unsigned short* __restrict__ H1b) {
    __shared__ float xs[64][65];
    __shared__ float w1s[64][128];
    int tid = threadIdx.x;
    size_t tok0 = (size_t)blockIdx.x * 64;
    int bimg = blockIdx.x >> 4;
    int hw0 = (blockIdx.x & 15) << 6;
    {
        int tok = tid >> 2, part = tid & 3;
        const float4* xp = (const float4*)(X1 + (tok0 + tok) * 64 + part * 16);
        float4 v0 = xp[0], v1 = xp[1], v2 = xp[2], v3 = xp[3];
        float s = v0.x + v0.y + v0.z + v0.w + v1.x + v1.y + v1.z + v1.w +
                  v2.x + v2.y + v2.z + v2.w + v3.x + v3.y + v3.z + v3.w;
        float ss = v0.x * v0.x + v0.y * v0.y + v0.z * v0.z + v0.w * v0.w +
                   v1.x * v1.x + v1.y * v1.y + v1.z * v1.z + v1.w * v1.w +
                   v2.x * v2.x + v2.y * v2.y + v2.z * v2.z + v2.w * v2.w +
                   v3.x * v3.x + v3.y * v3.y + v3.z * v3.z + v3.w * v3.w;
        s += __shfl_xor(s, 1, 64);
        ss += __shfl_xor(ss, 1, 64);
        s += __shfl_xor(s, 2, 64);
        ss += __shfl_xor(ss, 2, 64);
        float m = s * (1.f / 64.f);
        float var = ss * (1.f / 64.f) - m * m;
        float rstd = rsqrtf(var + 1e-5f);
        float vv[16] = {v0.x, v0.y, v0.z, v0.w, v1.x, v1.y, v1.z, v1.w,
                        v2.x, v2.y, v2.z, v2.w, v3.x, v3.y, v3.z, v3.w};
#pragma unroll
        for (int i = 0; i < 16; ++i) {
            int d = part * 16 + i;
            xs[tok][d] = (vv[i] - m) * rstd * g2[d] + be2[d];
        }
    }
    int tg = tid >> 5, cg = tid & 31;
#pragma unroll 1
    for (int half = 0; half < 2; ++half) {
        __syncthreads();
        for (int i = 0; i < 32; ++i) {
            int idx = i * 256 + tid;
            int d = idx >> 7, c = idx & 127;
            w1s[d][c] = W1[d * 256 + half * 128 + c];
        }
        __syncthreads();
        float acc[8][4];
#pragma unroll
        for (int t = 0; t < 8; ++t)
#pragma unroll
            for (int j = 0; j < 4; ++j)
                acc[t][j] = B1[half * 128 + j * 32 + cg];
#pragma unroll 2
        for (int d = 0; d < 64; ++d) {
            float w0 = w1s[d][cg];
            float w1v = w1s[d][32 + cg];
            float w2v = w1s[d][64 + cg];
            float w3v = w1s[d][96 + cg];
#pragma unroll
            for (int t = 0; t < 8; ++t) {
                float xv = xs[tg * 8 + t][d];
                acc[t][0] += xv * w0;
                acc[t][1] += xv * w1v;
                acc[t][2] += xv * w2v;
                acc[t][3] += xv * w3v;
            }
        }
#pragma unroll
        for (int t = 0; t < 8; ++t) {
            int hw = hw0 + tg * 8 + t;
#pragma unroll
            for (int j = 0; j < 4; ++j) {
                // hid = half*128 + j*32 + cg  ->  k0 = half*4 + j, hid_l = cg
                size_t gi = (((size_t)bimg * 8 + half * 4 + j) * 1024 + hw) * 32 + cg;
                H1b[gi] = f2bf(gelu_exact(acc[t][j]));
            }
        }
    }
}

// ---------------- K5b: prep DWT (tap-major) + W2T bf16 ----------------
__global__ __launch_bounds__(256) void k_prep(const float* __restrict__ DW,
                                              const float* __restrict__ W2,
                                              float* __restrict__ DWT,
                                              unsigned short* __restrict__ W2T) {
    int tid = threadIdx.x;
    for (int i = tid; i < 2304; i += 256) {
        int hid = i / 9, t = i - hid * 9;
        DWT[t * 256 + hid] = DW[i];
    }
    for (int i = tid; i < 16384; i += 256) {
        int n = i >> 8, k = i & 255;
        W2T[i] = f2bf(W2[k * 64 + n]);
    }
}

// ---------------- K6: fused dwconv3x3+GELU+lin2(MFMA)+bias+residual ----------
// H1 chunk-major: per tap a wave reads 1024 contiguous bytes.
__global__ __launch_bounds__(256) void k_leff2m(const unsigned short* __restrict__ H1b,
                                                const float* __restrict__ DWT,
                                                const float* __restrict__ DB,
                                                const unsigned short* __restrict__ W2T,
                                                const float* __restrict__ B2,
                                                float* __restrict__ out) {
    int tid = threadIdx.x;
    int wid = tid >> 6, lane = tid & 63;
    int mt = blockIdx.x * 4 + wid;   // 0..16383
    int b = mt >> 6;
    int rem = mt & 63;
    int h = rem >> 1;                // image row (wave-uniform)
    int w0 = (rem & 1) << 4;         // 0 or 16
    int lr = lane & 15;              // A-row (token) / C-col index
    int kg = lane >> 4;              // k-group 0..3
    int wA = w0 + lr;                // this lane's token w

    f32x4 acc[4];
#pragma unroll
    for (int n = 0; n < 4; ++n) acc[n] = (f32x4){0.f, 0.f, 0.f, 0.f};

#pragma unroll 1
    for (int k0 = 0; k0 < 8; ++k0) {
        int hid0 = k0 * 32 + kg * 8;
        size_t cbase = ((size_t)b * 8 + k0) * 1024;  // chunk image base (rows of 32 tokens)
        const f32x4* dbp = (const f32x4*)(DB + hid0);
        f32x4 d0 = dbp[0], d1 = dbp[1];
        float cv[8] = {d0.x, d0.y, d0.z, d0.w, d1.x, d1.y, d1.z, d1.w};
#pragma unroll
        for (int dr = -1; dr <= 1; ++dr) {
            int hr = h + dr;
            if (hr < 0 || hr > 31) continue;   // wave-uniform
#pragma unroll
            for (int dc = -1; dc <= 1; ++dc) {
                int wc = wA + dc;
                if (wc < 0 || wc > 31) continue;  // edge lanes only
                uint4 v = *(const uint4*)(H1b + ((cbase + (size_t)hr * 32 + wc) << 5) + kg * 8);
                const f32x4* wp = (const f32x4*)(DWT + ((dr + 1) * 3 + (dc + 1)) * 256 + hid0);
                f32x4 q0 = wp[0], q1 = wp[1];
                cv[0] += bflo(v.x) * q0.x;
                cv[1] += bfhi(v.x) * q0.y;
                cv[2] += bflo(v.y) * q0.z;
                cv[3] += bfhi(v.y) * q0.w;
                cv[4] += bflo(v.z) * q1.x;
                cv[5] += bfhi(v.z) * q1.y;
                cv[6] += bflo(v.w) * q1.z;
                cv[7] += bfhi(v.w) * q1.w;
            }
        }
        bfrag8 a;
#pragma unroll
        for (int e = 0; e < 8; ++e) a[e] = (short)f2bf(gelu_exact(cv[e]));
#pragma unroll
        for (int n = 0; n < 4; ++n) {
            bfrag8 bf = *(const bfrag8*)(W2T + ((size_t)(n * 16 + lr) * 256 + k0 * 32 + kg * 8));
            acc[n] = __builtin_amdgcn_mfma_f32_16x16x32_bf16(a, bf, acc[n], 0, 0, 0);
        }
    }
    // epilogue: C layout col=lane&15, row=(lane>>4)*4+reg
    size_t obase = (size_t)b * 1024 + (size_t)h * 32;
#pragma unroll
    for (int n = 0; n < 4; ++n) {
        int c = n * 16 + lr;
        float b2v = B2[c];
#pragma unroll
        for (int reg = 0; reg < 4; ++reg) {
            int rowTok = w0 + kg * 4 + reg;
            size_t gi = (obase + rowTok) * 64 + c;
            out[gi] += acc[n][reg] + b2v;
        }
    }
}

extern "C" void kernel_launch(void* const* d_in, const int* in_sizes, int n_in,
                              void* d_out, int out_size, void* d_ws, size_t ws_size,
                              hipStream_t stream) {
    const float* x = (const float*)d_in[0];
    const float* ln1_g = (const float*)d_in[1];
    const float* ln1_b = (const float*)d_in[2];
    const float* w_ll = (const float*)d_in[3];
    const float* w1 = (const float*)d_in[4];
    const float* w2 = (const float*)d_in[5];
    const float* b1 = (const float*)d_in[6];
    const float* b2 = (const float*)d_in[7];
    const float* ln2_g = (const float*)d_in[8];
    const float* ln2_b = (const float*)d_in[9];
    const float* lin1_w = (const float*)d_in[10];
    const float* lin1_b = (const float*)d_in[11];
    const float* dw_w = (const float*)d_in[12];
    const float* dw_b = (const float*)d_in[13];
    const float* lin2_w = (const float*)d_in[14];
    const float* lin2_b = (const float*)d_in[15];
    float* out = (float*)d_out;
    char* ws = (char*)d_ws;

    float* A = (float*)ws;
    float* HSr = (float*)(ws + 67108864);
    float* HSi = (float*)(ws + 167772160);
    float* LL = out;
    float* Y = A;
    unsigned short* H1b = (unsigned short*)ws;          // [0, 134.2MB)
    float* DWT = (float*)(ws + 167772160);              // reuses dead HSi
    unsigned short* W2T = (unsigned short*)(ws + 167772160 + 16384);

    k_ln1_t<<<dim3(4096), dim3(256), 0, stream>>>(x, ln1_g, ln1_b, A);
    k_fwd<<<dim3(16384), dim3(256), 0, stream>>>(A, w_ll, LL, HSr, HSi);
    k_mlp<<<dim3(1536), dim3(256), 0, stream>>>(HSr, HSi, w1, w2, b1, b2);
    k_inv<<<dim3(16384), dim3(256), 0, stream>>>(LL, HSr, HSi, Y);
    k_addt<<<dim3(4096), dim3(256), 0, stream>>>(Y, x, out);
    k_prep<<<dim3(1), dim3(256), 0, stream>>>(dw_w, lin2_w, DWT, W2T);
    k_leff1<<<dim3(4096), dim3(256), 0, stream>>>(out, ln2_g, ln2_b, lin1_w, lin1_b, H1b);
    k_leff2m<<<dim3(4096), dim3(256), 0, stream>>>(H1b, DWT, dw_b, W2T, b2, out);
}